// Round 21
// baseline (2440.224 us; speedup 1.0000x reference)
//
#include <hip/hip_runtime.h>

// VectorQuantizer on MI355X (gfx950)
// z:   [B=128, C=128, H=32, W=32] f32 -> pixel n = b*1024 + hw, channel stride 1024
// emb: [K=256, C=128] f32
// out: [quantized_st 16777216][indices 131072][commit 1][codebook 1] (f32)
//
// Exactness contract (verified absmax=0 rounds 2-20 -- DO NOT CHANGE):
//   d_k = fl( fl(zz - 2*s_k) + ee_k )
//   s_k = sequential fmaf over c ascending; zz = sequential fl(z*z) sum
//   first-occurrence argmin == min over u64 keys (d_bits<<32 | k), d > 0
//
// Round-21: occupancy-cap test + conflict-clean small tile.
//  - __launch_bounds__(256,6): r20 showed occupancy stuck at ~29% despite
//    halved LDS -> hypothesis: the 2nd arg is the effective waves/SIMD cap.
//    Body needs exactly 84 VGPR (r19/r20) <= 512/6=85, so cap 6 is legal.
//  - es pack-2 layout: 128 rows x 144B; row r holds code r (slots 0-3) and
//    code r+128 (slots 4-7). 9 units/row -> row index enters bank group mod 8.
//    read key ((cg>>2)^cg)&3 + half-offset 4*(cg>>4): 8 consecutive lanes
//    provably distinct (r19-validated criterion). Write key ((tx>>5)^(tx>>3))&3
//    matches reads (key depends only on code>>3). LDS ~23KB -> 6 blocks/CU.

typedef float f32x4 __attribute__((ext_vector_type(4)));
typedef unsigned long long u64;

#define VQ_C      128
#define VQ_K      256
#define VQ_HW     1024
#define VQ_CHW    (VQ_C * VQ_HW)
#define VQ_NPIX   131072
#define VQ_QELEMS 16777216
#define PXB       64
#define NBLK      (VQ_NPIX / PXB)     // 2048
#define CCH       16                  // channels per chunk
#define NCH       8
#define ESROW     144                 // packed es row stride (9 x 16B units)

// ws layout (floats): [0..255] ee[k]; [256..256+NBLK) per-block loss partials
__global__ void vq_prep(const float* __restrict__ emb, float* __restrict__ ws) {
    int k = threadIdx.x;               // 256 threads = 256 codes
    float s = 0.0f;
#pragma unroll
    for (int c = 0; c < VQ_C; ++c) {
        float e = emb[k * VQ_C + c];
        s = __fadd_rn(s, __fmul_rn(e, e));
    }
    ws[k] = s;
}

__global__ __launch_bounds__(256, 6) void vq_main(const float* __restrict__ z,
                                                  const float* __restrict__ emb,
                                                  const float* __restrict__ ee,
                                                  float* __restrict__ partials,
                                                  float* __restrict__ out) {
    __shared__ float zs[CCH * PXB];        // [c][px], 4 KB
    __shared__ char  es[128 * ESROW];      // packed swizzled e tile, 18 KB
    __shared__ float zzs[PXB];
    __shared__ int   iminS[PXB];
    __shared__ float red[4];

    const int tx = threadIdx.x;
    const int cg = tx & 31;                // code group: codes cg*8 .. +8
    const int pg = tx >> 5;                // px group:  px  pg*8 .. +8
    const int n0 = blockIdx.x * PXB;
    const int b  = n0 >> 10;
    const int hw0 = n0 & 1023;             // 64 | 1024 -> no b straddle
    const float* __restrict__ zb = z + (size_t)b * VQ_CHW + hw0;

    // ---- phase A: zz per pixel, exact sequential chain (wave 0; ordered
    //      before consumers by the first in-loop barrier)
    if (tx < PXB) {
        float zz = 0.0f;
#pragma unroll
        for (int c = 0; c < VQ_C; ++c) {
            float v = zb[c * VQ_HW + tx];  // 64-lane coalesced per c
            zz = __fadd_rn(zz, __fmul_rn(v, v));
        }
        zzs[tx] = zz;
    }

    float acc[8][8];
#pragma unroll
    for (int p = 0; p < 8; ++p)
#pragma unroll
        for (int o = 0; o < 8; ++o) acc[p][o] = 0.0f;

    const int ci   = tx >> 6;              // z-staging c-lane (wave id)
    const int px   = tx & 63;
    // staging: thread tx stages code tx into row tx&127, half tx>>7
    const int srow  = tx & 127;
    const int shoff = (tx >> 7) * 64;      // half offset in bytes (4 slots)
    const int swkey = ((tx >> 5) ^ (tx >> 3)) & 3;   // == code's key (code>>3 = cg)

    // hoisted hot-loop bases (byte pointers, loop-invariant)
    const char* const zbase = (const char*)zs + pg * 32;
    const char* const ebase = es + (cg & 15) * (8 * ESROW) + (cg >> 4) * 64;
    const int keysh = (((cg >> 2) ^ cg) & 3) << 4;   // read swizzle key, pre-shifted

#pragma unroll 1
    for (int ch = 0; ch < NCH; ++ch) {
        const int c0 = ch * CCH;
        if (ch) __syncthreads();           // protect tiles from overwrite

        // ---- stage z tile [c][px]: coalesced global reads, free LDS writes
#pragma unroll
        for (int i = 0; i < 4; ++i) {
            int c = i * 4 + ci;
            zs[c * PXB + px] = zb[(c0 + c) * VQ_HW + px];
        }
        // ---- stage e tile: thread tx = code tx; sequential coalesced loads,
        //      packed row + swizzled slot: group = (tx&7) + slot -> distinct
        //      per 8 consecutive lanes (row*9 == row mod 8)
        {
            const float* __restrict__ eg = emb + tx * VQ_C + c0;
            char* erow = es + srow * ESROW + shoff;
#pragma unroll
            for (int c4 = 0; c4 < 4; ++c4) {
                f32x4 v = *(const f32x4*)(eg + c4 * 4);
                *(f32x4*)(erow + ((c4 ^ swkey) << 4)) = v;
            }
        }
        __syncthreads();

        // ---- compute: 4 windows of 4 channels; immediate-offset ds reads
#pragma unroll 1
        for (int c4 = 0; c4 < 4; ++c4) {
            const char* eaddr = ebase + ((c4 << 4) ^ keysh);
            f32x4 ef[8];                   // 8 codes x 4 channels
#pragma unroll
            for (int o = 0; o < 8; ++o)
                ef[o] = *(const f32x4*)(eaddr + o * ESROW);  // offset:o*144

            f32x4 zf[4][2];                // [j][half]: 8 px of channel c4*4+j
#pragma unroll
            for (int j = 0; j < 4; ++j) {
                zf[j][0] = *(const f32x4*)(zbase + (c4 * 4 + j) * (PXB * 4));
                zf[j][1] = *(const f32x4*)(zbase + (c4 * 4 + j) * (PXB * 4) + 16);
            }
            // c ascending (j outer) => exact per-(px,code) fmaf chain
#pragma unroll
            for (int j = 0; j < 4; ++j)
#pragma unroll
                for (int o = 0; o < 8; ++o) {
                    float ev = ef[o][j];
#pragma unroll
                    for (int h = 0; h < 2; ++h)
#pragma unroll
                        for (int i = 0; i < 4; ++i)
                            acc[h * 4 + i][o] =
                                fmaf(zf[j][h][i], ev, acc[h * 4 + i][o]);
                }
        }
    }

    // ---- d + first-occurrence argmin (u64 keys; d > 0 so bit order = value order)
    float eev[8];
#pragma unroll
    for (int o = 0; o < 8; ++o) eev[o] = ee[cg * 8 + o];

#pragma unroll
    for (int p = 0; p < 8; ++p) {
        float zz = zzs[pg * 8 + p];
        u64 key = ~0ull;
#pragma unroll
        for (int o = 0; o < 8; ++o) {
            float a = acc[p][o];
            float d = __fadd_rn(__fsub_rn(zz, __fadd_rn(a, a)), eev[o]);
            union { float f; unsigned u; } du; du.f = d;
            u64 k2 = ((u64)du.u << 32) | (unsigned)(cg * 8 + o);
            if (k2 < key) key = k2;
        }
        // reduce across the 32 code-group threads (one half-wave)
#pragma unroll
        for (int st = 1; st < 32; st <<= 1) {
            u64 o2 = __shfl_xor(key, st, 32);
            if (o2 < key) key = o2;
        }
        if (cg == 0) iminS[pg * 8 + p] = (int)(key & 0xffffffffu);
    }
    __syncthreads();

    // ---- epilogue: thread -> pixel tx&63, channel-block tx>>6 (32 channels)
    const int cb = tx >> 6;
    const int im = iminS[px];
    const float* __restrict__ eq = emb + (size_t)im * VQ_C + cb * 32;
    const float* __restrict__ zp = zb + px;
    float* __restrict__ op = out + (size_t)b * VQ_CHW + hw0 + px;
    float lsum = 0.0f;
#pragma unroll
    for (int i = 0; i < 8; ++i) {
        f32x4 e4 = *(const f32x4*)(eq + i * 4);        // divergent L2 gather
#pragma unroll
        for (int j = 0; j < 4; ++j) {
            int c = cb * 32 + i * 4 + j;
            float zv   = zp[c * VQ_HW];                // L2-hot, exact bits
            float diff = __fsub_rn(e4[j], zv);
            op[c * VQ_HW] = __fadd_rn(zv, diff);       // coalesced per c
            lsum = fmaf(diff, diff, lsum);
        }
    }
    if (tx < PXB) out[VQ_QELEMS + n0 + tx] = (float)iminS[tx];

    // ---- loss partial
#pragma unroll
    for (int off = 32; off > 0; off >>= 1) lsum += __shfl_down(lsum, off, 64);
    if ((tx & 63) == 0) red[tx >> 6] = lsum;
    __syncthreads();
    if (tx == 0)
        partials[blockIdx.x] = (red[0] + red[1]) + (red[2] + red[3]);
}

__global__ void vq_fin(const float* __restrict__ partials, float* __restrict__ out) {
    double acc = 0.0;
    for (int i = 0; i < NBLK; ++i) acc += (double)partials[i];
    float m = (float)(acc * (1.0 / (double)VQ_QELEMS));
    out[VQ_QELEMS + VQ_NPIX + 0] = 0.25f * m;  // commitment
    out[VQ_QELEMS + VQ_NPIX + 1] = m;          // codebook
}

extern "C" void kernel_launch(void* const* d_in, const int* in_sizes, int n_in,
                              void* d_out, int out_size, void* d_ws, size_t ws_size,
                              hipStream_t stream) {
    const float* z   = (const float*)d_in[0];
    const float* emb = (const float*)d_in[1];
    float* out = (float*)d_out;
    float* ws  = (float*)d_ws;            // [0..255]=ee, [256..)=partials

    vq_prep<<<1, 256, 0, stream>>>(emb, ws);
    vq_main<<<NBLK, 256, 0, stream>>>(z, emb, ws, ws + 256, out);
    vq_fin<<<1, 1, 0, stream>>>(ws + 256, out);
}

// Round 22
// 228.893 us; speedup vs baseline: 10.6610x; 10.6610x over previous
//
#include <hip/hip_runtime.h>

// VectorQuantizer on MI355X (gfx950)
// z:   [B=128, C=128, H=32, W=32] f32 -> pixel n = b*1024 + hw, channel stride 1024
// emb: [K=256, C=128] f32
// out: [quantized_st 16777216][indices 131072][commit 1][codebook 1] (f32)
//
// Exactness contract (verified absmax=0 rounds 2-21 -- DO NOT CHANGE):
//   d_k = fl( fl(zz - 2*s_k) + ee_k )
//   s_k = sequential fmaf over c ascending; zz = sequential fl(z*z) sum
//   first-occurrence argmin == min over u64 keys (d_bits<<32 | k), d > 0
//
// Round-22 = round-21 VERBATIM except __launch_bounds__(256,6) -> (256,4).
// r21 proved: (a) the 2nd arg gates achieved occupancy (29->53%); (b) cap 6
// (85 VGPR) spills this tile catastrophically; (c) the pack-2 es layout is
// conflict-FREE on HW (0 counted even while spilling). Cap 4 = 128 VGPR:
// above the ~84-110 the 256-thread body schedules into (r19, cap 168), while
// raising the occupancy gate 3 -> 4 waves/SIMD. LDS 23KB allows 6 blocks/CU,
// so the gate is binding. Single-variable test on a conflict-clean base.

typedef float f32x4 __attribute__((ext_vector_type(4)));
typedef unsigned long long u64;

#define VQ_C      128
#define VQ_K      256
#define VQ_HW     1024
#define VQ_CHW    (VQ_C * VQ_HW)
#define VQ_NPIX   131072
#define VQ_QELEMS 16777216
#define PXB       64
#define NBLK      (VQ_NPIX / PXB)     // 2048
#define CCH       16                  // channels per chunk
#define NCH       8
#define ESROW     144                 // packed es row stride (9 x 16B units)

// ws layout (floats): [0..255] ee[k]; [256..256+NBLK) per-block loss partials
__global__ void vq_prep(const float* __restrict__ emb, float* __restrict__ ws) {
    int k = threadIdx.x;               // 256 threads = 256 codes
    float s = 0.0f;
#pragma unroll
    for (int c = 0; c < VQ_C; ++c) {
        float e = emb[k * VQ_C + c];
        s = __fadd_rn(s, __fmul_rn(e, e));
    }
    ws[k] = s;
}

__global__ __launch_bounds__(256, 4) void vq_main(const float* __restrict__ z,
                                                  const float* __restrict__ emb,
                                                  const float* __restrict__ ee,
                                                  float* __restrict__ partials,
                                                  float* __restrict__ out) {
    __shared__ float zs[CCH * PXB];        // [c][px], 4 KB
    __shared__ char  es[128 * ESROW];      // packed swizzled e tile, 18 KB
    __shared__ float zzs[PXB];
    __shared__ int   iminS[PXB];
    __shared__ float red[4];

    const int tx = threadIdx.x;
    const int cg = tx & 31;                // code group: codes cg*8 .. +8
    const int pg = tx >> 5;                // px group:  px  pg*8 .. +8
    const int n0 = blockIdx.x * PXB;
    const int b  = n0 >> 10;
    const int hw0 = n0 & 1023;             // 64 | 1024 -> no b straddle
    const float* __restrict__ zb = z + (size_t)b * VQ_CHW + hw0;

    // ---- phase A: zz per pixel, exact sequential chain (wave 0; ordered
    //      before consumers by the first in-loop barrier)
    if (tx < PXB) {
        float zz = 0.0f;
#pragma unroll
        for (int c = 0; c < VQ_C; ++c) {
            float v = zb[c * VQ_HW + tx];  // 64-lane coalesced per c
            zz = __fadd_rn(zz, __fmul_rn(v, v));
        }
        zzs[tx] = zz;
    }

    float acc[8][8];
#pragma unroll
    for (int p = 0; p < 8; ++p)
#pragma unroll
        for (int o = 0; o < 8; ++o) acc[p][o] = 0.0f;

    const int ci   = tx >> 6;              // z-staging c-lane (wave id)
    const int px   = tx & 63;
    // staging: thread tx stages code tx into row tx&127, half tx>>7
    const int srow  = tx & 127;
    const int shoff = (tx >> 7) * 64;      // half offset in bytes (4 slots)
    const int swkey = ((tx >> 5) ^ (tx >> 3)) & 3;   // == code's key (code>>3 = cg)

    // hoisted hot-loop bases (byte pointers, loop-invariant)
    const char* const zbase = (const char*)zs + pg * 32;
    const char* const ebase = es + (cg & 15) * (8 * ESROW) + (cg >> 4) * 64;
    const int keysh = (((cg >> 2) ^ cg) & 3) << 4;   // read swizzle key, pre-shifted

#pragma unroll 1
    for (int ch = 0; ch < NCH; ++ch) {
        const int c0 = ch * CCH;
        if (ch) __syncthreads();           // protect tiles from overwrite

        // ---- stage z tile [c][px]: coalesced global reads, free LDS writes
#pragma unroll
        for (int i = 0; i < 4; ++i) {
            int c = i * 4 + ci;
            zs[c * PXB + px] = zb[(c0 + c) * VQ_HW + px];
        }
        // ---- stage e tile: thread tx = code tx; sequential coalesced loads,
        //      packed row + swizzled slot: group = (tx&7) + slot -> distinct
        //      per 8 consecutive lanes (row*9 == row mod 8)
        {
            const float* __restrict__ eg = emb + tx * VQ_C + c0;
            char* erow = es + srow * ESROW + shoff;
#pragma unroll
            for (int c4 = 0; c4 < 4; ++c4) {
                f32x4 v = *(const f32x4*)(eg + c4 * 4);
                *(f32x4*)(erow + ((c4 ^ swkey) << 4)) = v;
            }
        }
        __syncthreads();

        // ---- compute: 4 windows of 4 channels; immediate-offset ds reads
#pragma unroll 1
        for (int c4 = 0; c4 < 4; ++c4) {
            const char* eaddr = ebase + ((c4 << 4) ^ keysh);
            f32x4 ef[8];                   // 8 codes x 4 channels
#pragma unroll
            for (int o = 0; o < 8; ++o)
                ef[o] = *(const f32x4*)(eaddr + o * ESROW);  // offset:o*144

            f32x4 zf[4][2];                // [j][half]: 8 px of channel c4*4+j
#pragma unroll
            for (int j = 0; j < 4; ++j) {
                zf[j][0] = *(const f32x4*)(zbase + (c4 * 4 + j) * (PXB * 4));
                zf[j][1] = *(const f32x4*)(zbase + (c4 * 4 + j) * (PXB * 4) + 16);
            }
            // c ascending (j outer) => exact per-(px,code) fmaf chain
#pragma unroll
            for (int j = 0; j < 4; ++j)
#pragma unroll
                for (int o = 0; o < 8; ++o) {
                    float ev = ef[o][j];
#pragma unroll
                    for (int h = 0; h < 2; ++h)
#pragma unroll
                        for (int i = 0; i < 4; ++i)
                            acc[h * 4 + i][o] =
                                fmaf(zf[j][h][i], ev, acc[h * 4 + i][o]);
                }
        }
    }

    // ---- d + first-occurrence argmin (u64 keys; d > 0 so bit order = value order)
    float eev[8];
#pragma unroll
    for (int o = 0; o < 8; ++o) eev[o] = ee[cg * 8 + o];

#pragma unroll
    for (int p = 0; p < 8; ++p) {
        float zz = zzs[pg * 8 + p];
        u64 key = ~0ull;
#pragma unroll
        for (int o = 0; o < 8; ++o) {
            float a = acc[p][o];
            float d = __fadd_rn(__fsub_rn(zz, __fadd_rn(a, a)), eev[o]);
            union { float f; unsigned u; } du; du.f = d;
            u64 k2 = ((u64)du.u << 32) | (unsigned)(cg * 8 + o);
            if (k2 < key) key = k2;
        }
        // reduce across the 32 code-group threads (one half-wave)
#pragma unroll
        for (int st = 1; st < 32; st <<= 1) {
            u64 o2 = __shfl_xor(key, st, 32);
            if (o2 < key) key = o2;
        }
        if (cg == 0) iminS[pg * 8 + p] = (int)(key & 0xffffffffu);
    }
    __syncthreads();

    // ---- epilogue: thread -> pixel tx&63, channel-block tx>>6 (32 channels)
    const int cb = tx >> 6;
    const int im = iminS[px];
    const float* __restrict__ eq = emb + (size_t)im * VQ_C + cb * 32;
    const float* __restrict__ zp = zb + px;
    float* __restrict__ op = out + (size_t)b * VQ_CHW + hw0 + px;
    float lsum = 0.0f;
#pragma unroll
    for (int i = 0; i < 8; ++i) {
        f32x4 e4 = *(const f32x4*)(eq + i * 4);        // divergent L2 gather
#pragma unroll
        for (int j = 0; j < 4; ++j) {
            int c = cb * 32 + i * 4 + j;
            float zv   = zp[c * VQ_HW];                // L2-hot, exact bits
            float diff = __fsub_rn(e4[j], zv);
            op[c * VQ_HW] = __fadd_rn(zv, diff);       // coalesced per c
            lsum = fmaf(diff, diff, lsum);
        }
    }
    if (tx < PXB) out[VQ_QELEMS + n0 + tx] = (float)iminS[tx];

    // ---- loss partial
#pragma unroll
    for (int off = 32; off > 0; off >>= 1) lsum += __shfl_down(lsum, off, 64);
    if ((tx & 63) == 0) red[tx >> 6] = lsum;
    __syncthreads();
    if (tx == 0)
        partials[blockIdx.x] = (red[0] + red[1]) + (red[2] + red[3]);
}

__global__ void vq_fin(const float* __restrict__ partials, float* __restrict__ out) {
    double acc = 0.0;
    for (int i = 0; i < NBLK; ++i) acc += (double)partials[i];
    float m = (float)(acc * (1.0 / (double)VQ_QELEMS));
    out[VQ_QELEMS + VQ_NPIX + 0] = 0.25f * m;  // commitment
    out[VQ_QELEMS + VQ_NPIX + 1] = m;          // codebook
}

extern "C" void kernel_launch(void* const* d_in, const int* in_sizes, int n_in,
                              void* d_out, int out_size, void* d_ws, size_t ws_size,
                              hipStream_t stream) {
    const float* z   = (const float*)d_in[0];
    const float* emb = (const float*)d_in[1];
    float* out = (float*)d_out;
    float* ws  = (float*)d_ws;            // [0..255]=ee, [256..)=partials

    vq_prep<<<1, 256, 0, stream>>>(emb, ws);
    vq_main<<<NBLK, 256, 0, stream>>>(z, emb, ws, ws + 256, out);
    vq_fin<<<1, 1, 0, stream>>>(ws + 256, out);
}

// Round 23
// 166.944 us; speedup vs baseline: 14.6170x; 1.3711x over previous
//
#include <hip/hip_runtime.h>

// VectorQuantizer on MI355X (gfx950)
// z:   [B=128, C=128, H=32, W=32] f32 -> pixel n = b*1024 + hw, channel stride 1024
// emb: [K=256, C=128] f32
// out: [quantized_st 16777216][indices 131072][commit 1][codebook 1] (f32)
//
// Exactness contract (verified absmax=0 rounds 2-22 -- DO NOT CHANGE):
//   d_k = fl( fl(zz - 2*s_k) + ee_k )
//   s_k = sequential fmaf over c ascending; zz = sequential fl(z*z) sum
//   first-occurrence argmin == min over u64 keys (d_bits<<32 | k), d > 0
//
// Round-23 = round-19 VERBATIM (160.5us, 0 conflicts, VGPR 84, cap 3) with the
// inner product converted to PACKED f32 FMA: adjacent-pixel pairs in f32x2 via
// __builtin_elementwise_fma -> llvm.fma.v2f32 -> v_pk_fma_f32 (full-rate on
// CDNA since gfx90a). Each lane-half remains an independent sequential fused-RN
// chain over c ascending => bit-identical d. Halves FMA issue (131K -> 65K
// cyc/SIMD), freeing issue slots for latency hiding. Occupancy/LDS untouched.

typedef float f32x4 __attribute__((ext_vector_type(4)));
typedef float f32x2 __attribute__((ext_vector_type(2)));
typedef unsigned long long u64;

#define VQ_C      128
#define VQ_K      256
#define VQ_HW     1024
#define VQ_CHW    (VQ_C * VQ_HW)
#define VQ_NPIX   131072
#define VQ_QELEMS 16777216
#define PXB       64
#define NBLK      (VQ_NPIX / PXB)     // 2048
#define CCH       32                  // channels per chunk
#define NCH       4
#define EROW      144                 // es row stride bytes (8x16B + 16B pad)

// ws layout (floats): [0..255] ee[k]; [256..256+NBLK) per-block loss partials
__global__ void vq_prep(const float* __restrict__ emb, float* __restrict__ ws) {
    int k = threadIdx.x;               // 256 threads = 256 codes
    float s = 0.0f;
#pragma unroll
    for (int c = 0; c < VQ_C; ++c) {
        float e = emb[k * VQ_C + c];
        s = __fadd_rn(s, __fmul_rn(e, e));
    }
    ws[k] = s;
}

__global__ __launch_bounds__(256, 3) void vq_main(const float* __restrict__ z,
                                                  const float* __restrict__ emb,
                                                  const float* __restrict__ ee,
                                                  float* __restrict__ partials,
                                                  float* __restrict__ out) {
    __shared__ float zs[CCH * PXB];        // [c][px], 8 KB
    __shared__ char  es[VQ_K * EROW];      // padded swizzled e tile, 36 KB
    __shared__ float zzs[PXB];
    __shared__ int   iminS[PXB];
    __shared__ float red[4];

    const int tx = threadIdx.x;
    const int cg = tx & 31;                // code group: codes cg*8 .. +8
    const int pg = tx >> 5;                // px group:  px  pg*8 .. +8
    const int n0 = blockIdx.x * PXB;
    const int b  = n0 >> 10;
    const int hw0 = n0 & 1023;             // 64 | 1024 -> no b straddle
    const float* __restrict__ zb = z + (size_t)b * VQ_CHW + hw0;

    // ---- phase A: zz per pixel, exact sequential chain (wave 0; ordered
    //      before consumers by the first in-loop barrier)
    if (tx < PXB) {
        float zz = 0.0f;
#pragma unroll
        for (int c = 0; c < VQ_C; ++c) {
            float v = zb[c * VQ_HW + tx];  // 64-lane coalesced per c
            zz = __fadd_rn(zz, __fmul_rn(v, v));
        }
        zzs[tx] = zz;
    }

    // packed accumulators: acc2[ph][o] = (acc[2ph][o], acc[2ph+1][o])
    f32x2 acc2[4][8];
#pragma unroll
    for (int ph = 0; ph < 4; ++ph)
#pragma unroll
        for (int o = 0; o < 8; ++o) acc2[ph][o] = (f32x2){0.0f, 0.0f};

    const int ci  = tx >> 6;               // z-staging c-lane (wave id)
    const int px  = tx & 63;
    const int swx = ((tx >> 6) ^ (tx >> 3)) & 7;   // write swizzle key (r18-proven)

    // hoisted hot-loop bases (byte pointers, loop-invariant)
    const char* const zbase = (const char*)zs + pg * 32;
    const char* const ebase = es + cg * (8 * EROW);
    const int keysh = (((cg >> 3) ^ cg) & 7) << 4; // read swizzle key (r18-proven)

#pragma unroll 1
    for (int ch = 0; ch < NCH; ++ch) {
        const int c0 = ch * CCH;
        if (ch) __syncthreads();           // protect tiles from overwrite

        // ---- stage z tile [c][px]: coalesced global reads, free LDS writes
#pragma unroll
        for (int i = 0; i < 8; ++i) {
            int c = i * 4 + ci;
            zs[c * PXB + px] = zb[(c0 + c) * VQ_HW + px];
        }
        // ---- stage e tile: thread tx = code row; sequential coalesced loads,
        //      swizzled slot + 144B padded rows -> conflict-free (r19: 0)
        {
            const float* __restrict__ eg = emb + tx * VQ_C + c0;
            char* erow = es + tx * EROW;
#pragma unroll
            for (int c4 = 0; c4 < 8; ++c4) {
                f32x4 v = *(const f32x4*)(eg + c4 * 4);
                *(f32x4*)(erow + ((c4 ^ swx) << 4)) = v;
            }
        }
        __syncthreads();

        // ---- compute: 8 windows of 4 channels; immediate-offset ds reads;
        //      inner product as v_pk_fma_f32 (px pairs)
#pragma unroll 1
        for (int c4 = 0; c4 < 8; ++c4) {
            const char* eaddr = ebase + ((c4 << 4) ^ keysh);
            f32x4 ef[8];                   // 8 codes x 4 channels
#pragma unroll
            for (int o = 0; o < 8; ++o)
                ef[o] = *(const f32x4*)(eaddr + o * EROW);   // offset:o*144

            f32x4 zf[4][2];                // [j][half]: 8 px of channel c4*4+j
#pragma unroll
            for (int j = 0; j < 4; ++j) {
                zf[j][0] = *(const f32x4*)(zbase + (c4 * 4 + j) * (PXB * 4));
                zf[j][1] = *(const f32x4*)(zbase + (c4 * 4 + j) * (PXB * 4) + 16);
            }
            // c ascending (j outer) => exact per-(px,code) fused-RN chain
#pragma unroll
            for (int j = 0; j < 4; ++j) {
                f32x2 zp[4];               // 4 px-pairs of channel c4*4+j
                zp[0] = (f32x2){zf[j][0][0], zf[j][0][1]};
                zp[1] = (f32x2){zf[j][0][2], zf[j][0][3]};
                zp[2] = (f32x2){zf[j][1][0], zf[j][1][1]};
                zp[3] = (f32x2){zf[j][1][2], zf[j][1][3]};
#pragma unroll
                for (int o = 0; o < 8; ++o) {
                    float ev = ef[o][j];
                    f32x2 ev2 = (f32x2){ev, ev};
#pragma unroll
                    for (int ph = 0; ph < 4; ++ph)
                        acc2[ph][o] = __builtin_elementwise_fma(zp[ph], ev2,
                                                                acc2[ph][o]);
                }
            }
        }
    }

    // ---- d + first-occurrence argmin (u64 keys; d > 0 so bit order = value order)
    float eev[8];
#pragma unroll
    for (int o = 0; o < 8; ++o) eev[o] = ee[cg * 8 + o];

#pragma unroll
    for (int p = 0; p < 8; ++p) {
        float zz = zzs[pg * 8 + p];
        u64 key = ~0ull;
#pragma unroll
        for (int o = 0; o < 8; ++o) {
            float a = acc2[p >> 1][o][p & 1];   // static after unroll
            float d = __fadd_rn(__fsub_rn(zz, __fadd_rn(a, a)), eev[o]);
            union { float f; unsigned u; } du; du.f = d;
            u64 k2 = ((u64)du.u << 32) | (unsigned)(cg * 8 + o);
            if (k2 < key) key = k2;
        }
        // reduce across the 32 code-group threads (one half-wave)
#pragma unroll
        for (int st = 1; st < 32; st <<= 1) {
            u64 o2 = __shfl_xor(key, st, 32);
            if (o2 < key) key = o2;
        }
        if (cg == 0) iminS[pg * 8 + p] = (int)(key & 0xffffffffu);
    }
    __syncthreads();

    // ---- epilogue: thread -> pixel tx&63, channel-block tx>>6 (32 channels)
    const int cb = tx >> 6;
    const int im = iminS[px];
    const float* __restrict__ eq = emb + (size_t)im * VQ_C + cb * 32;
    const float* __restrict__ zp2 = zb + px;
    float* __restrict__ op = out + (size_t)b * VQ_CHW + hw0 + px;
    float lsum = 0.0f;
#pragma unroll
    for (int i = 0; i < 8; ++i) {
        f32x4 e4 = *(const f32x4*)(eq + i * 4);        // divergent L2 gather
#pragma unroll
        for (int j = 0; j < 4; ++j) {
            int c = cb * 32 + i * 4 + j;
            float zv   = zp2[c * VQ_HW];               // L2-hot, exact bits
            float diff = __fsub_rn(e4[j], zv);
            op[c * VQ_HW] = __fadd_rn(zv, diff);       // coalesced per c
            lsum = fmaf(diff, diff, lsum);
        }
    }
    if (tx < PXB) out[VQ_QELEMS + n0 + tx] = (float)iminS[tx];

    // ---- loss partial
#pragma unroll
    for (int off = 32; off > 0; off >>= 1) lsum += __shfl_down(lsum, off, 64);
    if ((tx & 63) == 0) red[tx >> 6] = lsum;
    __syncthreads();
    if (tx == 0)
        partials[blockIdx.x] = (red[0] + red[1]) + (red[2] + red[3]);
}

__global__ void vq_fin(const float* __restrict__ partials, float* __restrict__ out) {
    double acc = 0.0;
    for (int i = 0; i < NBLK; ++i) acc += (double)partials[i];
    float m = (float)(acc * (1.0 / (double)VQ_QELEMS));
    out[VQ_QELEMS + VQ_NPIX + 0] = 0.25f * m;  // commitment
    out[VQ_QELEMS + VQ_NPIX + 1] = m;          // codebook
}

extern "C" void kernel_launch(void* const* d_in, const int* in_sizes, int n_in,
                              void* d_out, int out_size, void* d_ws, size_t ws_size,
                              hipStream_t stream) {
    const float* z   = (const float*)d_in[0];
    const float* emb = (const float*)d_in[1];
    float* out = (float*)d_out;
    float* ws  = (float*)d_ws;            // [0..255]=ee, [256..)=partials

    vq_prep<<<1, 256, 0, stream>>>(emb, ws);
    vq_main<<<NBLK, 256, 0, stream>>>(z, emb, ws, ws + 256, out);
    vq_fin<<<1, 1, 0, stream>>>(ws + 256, out);
}